// Round 5
// baseline (642.131 us; speedup 1.0000x reference)
//
#include <hip/hip_runtime.h>
#include <hip/hip_bf16.h>

// Swin block: B=8, H=W=128, C=192, NH=6, HD=32, WS=8, SHIFT=4, N=64, NW=256
// ROUND 11 (= R10 resubmit after infra failure; one redundant barrier removed).
// Single fused kernel. The MLP is token-local and P1's read address equals
// P4's write address, so the o1 residual stream lives entirely in LDS
// (fp32 [64][192] overlaying Ks+Vt). Saves ~300MB HBM + a launch + an LN pass.
// Softmax bias+mask precomputed per window-type (4) into d_ws, loaded into 32
// VGPRs per wave at kernel start (removes rpbs gather + its bank conflicts).
// Phase-2 'which' made wave-uniform (no per-element QKV scatter branches).

typedef __hip_bfloat16 bf16;
typedef short bf16x8 __attribute__((ext_vector_type(8)));   // 8 bf16 = 4 VGPRs
typedef float f32x4 __attribute__((ext_vector_type(4)));

__device__ __forceinline__ bf16 f2b(float f) { return __float2bfloat16(f); }
// swizzled LDS element offset: XOR row low bits into the 16B-block index.
__device__ __forceinline__ int sw(int row, int col, int stride) {
    return row * stride + (col ^ ((row & 7) << 3));
}
#define NTS(v, p) __builtin_nontemporal_store(v, p)

// workspace layout - fragment-ordered bf16 weights, then f32 bias table:
// weight element ((cb*KS + ks)*64 + lane)*8 + j == W[cb*16+(lane&15)][ks*32+(lane>>4)*8+j]
#define WQ_OFF 0        // qkv_w  [576][192]  cb=36 KS=6
#define WP_OFF 110592   // proj_w [192][192]  cb=12 KS=6
#define W1_OFF 147456   // fc1_w  [768][192]  cb=48 KS=6
#define W2_OFF 294912   // fc2_w  [192][768]  cb=12 KS=24
#define WS_ELEMS 442368
// bias table: f32 [type(4)][u(24)][lane(64)][n(4)][r(4)]  (393216 B)

// ---- K0: one-shot fp32 -> bf16 fragment-order weight conversion ------------
__global__ __launch_bounds__(256) void w_cvt(const float* __restrict__ qw,
                                             const float* __restrict__ pw,
                                             const float* __restrict__ w1,
                                             const float* __restrict__ w2,
                                             bf16* __restrict__ ws) {
    int t = blockIdx.x * 256 + threadIdx.x;   // one 8-elem group per thread
    if (t >= 55296) return;                   // 442368/8
    const float* src; int K; int base; int g;
    if (t < 13824)      { src = qw; K = 192; base = WQ_OFF; g = t; }
    else if (t < 18432) { src = pw; K = 192; base = WP_OFF; g = t - 13824; }
    else if (t < 36864) { src = w1; K = 192; base = W1_OFF; g = t - 18432; }
    else                { src = w2; K = 768; base = W2_OFF; g = t - 36864; }
    int KS = K >> 5;
    int cb   = g / (KS * 64);
    int rem  = g % (KS * 64);
    int ks   = rem >> 6;
    int lane = rem & 63;
    int row  = cb * 16 + (lane & 15);
    int k0   = ks * 32 + (lane >> 4) * 8;
    bf16* dst = ws + base + (size_t)g * 8;
    const float* s = src + (size_t)row * K + k0;
#pragma unroll
    for (int j = 0; j < 8; ++j) dst[j] = f2b(s[j]);
}

// ---- K0b: bias+mask table per window type, in softmax fragment order -------
__global__ __launch_bounds__(256) void b_cvt(const float* __restrict__ rpb,
                                             float* __restrict__ bws) {
    int t = blockIdx.x * 256 + threadIdx.x;
    if (t >= 98304) return;                   // 4*24*64*16
    int r = t & 3, n = (t >> 2) & 3, lane = (t >> 4) & 63;
    int rest = t >> 10;
    int u = rest % 24, type = rest / 24;
    int h = u >> 2, mq = u & 3;
    int q   = mq * 16 + (lane >> 4) * 4 + r;
    int key = n * 16 + (lane & 15);
    int yi = q >> 3, xi = q & 7, yj = key >> 3, xj = key & 7;
    float b = rpb[((yi - yj + 7) * 15 + (xi - xj + 7)) * 6 + h];
    int ty = type >> 1, tx = type & 1;
    int li = (ty ? (yi < 4 ? 1 : 2) : 0) * 3 + (tx ? (xi < 4 ? 1 : 2) : 0);
    int lj = (ty ? (yj < 4 ? 1 : 2) : 0) * 3 + (tx ? (xj < 4 ? 1 : 2) : 0);
    if (li != lj) b -= 100.f;
    bws[t] = b;
}

// ---- K1: fully fused Swin block, one window (64 tokens) per block ----------
__global__ __launch_bounds__(1024, 4) void k_all(const float* __restrict__ x,
                                                 const float* __restrict__ g,
                                                 const float* __restrict__ bt,
                                                 const bf16* __restrict__ wsb,
                                                 const float* __restrict__ bws,
                                                 const float* __restrict__ qbias,
                                                 const float* __restrict__ pbias,
                                                 const float* __restrict__ g2,
                                                 const float* __restrict__ bt2,
                                                 const float* __restrict__ b1,
                                                 const float* __restrict__ b2,
                                                 float* __restrict__ out) {
    // LDS (128 KB exactly), regions reused across phases:
    //  R0 [0,24576)      Qs [64][192]swz          | P5+: As (LN2 tile)
    //  R1 [24576,49152)  Ks [64][192]swz          | P4+: o1f fp32 [64][192] (48KB
    //  R2 [49152,73728)  Vt [6][32][64]swz        |      spans R1+R2)
    //  R3 [73728,98304)  A (LN1) == AO (attn out)
    //  R4 [98304,131072) Pb 16x2KB                | P6+: Hs [2][64][128]swz bf16
    __shared__ __align__(16) char SM[131072];
    bf16* Qs = (bf16*)(SM);
    bf16* Ks = (bf16*)(SM + 24576);
    bf16* Vt = (bf16*)(SM + 49152);
    bf16* A  = (bf16*)(SM + 73728);
    bf16* AO = (bf16*)(SM + 73728);
    bf16* Pb = (bf16*)(SM + 98304);
    float* o1f = (float*)(SM + 24576);   // overlays Ks+Vt (dead after P3)
    bf16* As   = (bf16*)(SM);            // overlays Qs (dead after P3)
    bf16* Hs0  = (bf16*)(SM + 98304);    // overlays Pb (dead after P3)
    bf16* Hs1  = (bf16*)(SM + 114688);

    int wid = blockIdx.x;
    int bz = wid >> 8, widx = wid & 255;
    int wh = widx >> 4, ww = widx & 15;
    int tid = threadIdx.x, wave = tid >> 6, lane = tid & 63;
    int l15 = lane & 15, l4 = lane >> 4;
    int kk0 = l4 << 3;
    int mq = wave & 3, cg = wave >> 2;
    const float SC = 0.1767766952966369f;  // 1/sqrt(32)

    // --- Phase 0: issue this wave's softmax bias loads (used in P3) ---------
    int wtype = ((wh == 15) ? 2 : 0) | ((ww == 15) ? 1 : 0);
    f32x4 bias4[2][4];
    {
        const float* bp = bws + (((size_t)wtype * 24 + wave) * 64 + lane) * 16;
#pragma unroll
        for (int n = 0; n < 4; ++n) bias4[0][n] = *(const f32x4*)&bp[n * 4];
        if (wave < 8) {
            const float* bp2 = bws + (((size_t)wtype * 24 + wave + 16) * 64 + lane) * 16;
#pragma unroll
            for (int n = 0; n < 4; ++n) bias4[1][n] = *(const f32x4*)&bp2[n * 4];
        }
    }

    // --- Phase 1: LN1 + cyclic shift -> A -----------------------------------
    {
        float g0 = g[lane], g1 = g[lane + 64], gx = g[lane + 128];
        float c0 = bt[lane], c1 = bt[lane + 64], c2 = bt[lane + 128];
        for (int t = wave; t < 64; t += 16) {
            int i = t >> 3, j = t & 7;
            int shr = (wh * 8 + i + 4) & 127;   // roll(-4)
            int shc = (ww * 8 + j + 4) & 127;
            const float* px = x + ((size_t)bz * 16384 + shr * 128 + shc) * 192;
            float v0 = px[lane], v1 = px[lane + 64], v2 = px[lane + 128];
            float s = v0 + v1 + v2, ss = v0 * v0 + v1 * v1 + v2 * v2;
#pragma unroll
            for (int o = 32; o > 0; o >>= 1) { s += __shfl_xor(s, o); ss += __shfl_xor(ss, o); }
            float mu = s * (1.f / 192.f);
            float var = fmaxf(ss * (1.f / 192.f) - mu * mu, 0.f);
            float rs = rsqrtf(var + 1e-5f);
            A[sw(t, lane, 192)]       = f2b((v0 - mu) * rs * g0 + c0);
            A[sw(t, lane + 64, 192)]  = f2b((v1 - mu) * rs * g1 + c1);
            A[sw(t, lane + 128, 192)] = f2b((v2 - mu) * rs * gx + c2);
        }
    }
    __syncthreads();

    // --- Phase 2: QKV GEMM (M=64, N=576, K=192), 'which' wave-uniform -------
    {
        const bf16* Wq = wsb + WQ_OFF;
        bf16x8 a6[6];
#pragma unroll
        for (int ks = 0; ks < 6; ++ks)
            a6[ks] = *(const bf16x8*)&A[sw(mq * 16 + l15, ks * 32 + kk0, 192)];
#pragma unroll 1
        for (int which = 0; which < 3; ++which) {
            int cb0 = which * 12 + cg * 3;
            f32x4 acc[3];
#pragma unroll
            for (int n = 0; n < 3; ++n) acc[n] = (f32x4){0.f, 0.f, 0.f, 0.f};
#pragma unroll
            for (int ks = 0; ks < 6; ++ks) {
                bf16x8 bb[3];
#pragma unroll
                for (int n = 0; n < 3; ++n)
                    bb[n] = *(const bf16x8*)&Wq[((cb0 + n) * 6 + ks) * 512 + (lane << 3)];
#pragma unroll
                for (int n = 0; n < 3; ++n)
                    acc[n] = __builtin_amdgcn_mfma_f32_16x16x32_bf16(a6[ks], bb[n], acc[n], 0, 0, 0);
            }
#pragma unroll
            for (int n = 0; n < 3; ++n) {
                int cc = cg * 48 + n * 16 + l15;          // col within matrix
                float qb = qbias[which * 192 + cc];
                if (which == 0) {
#pragma unroll
                    for (int r = 0; r < 4; ++r) {
                        int tok = mq * 16 + (l4 << 2) + r;
                        Qs[sw(tok, cc, 192)] = f2b((acc[n][r] + qb) * SC);
                    }
                } else if (which == 1) {
#pragma unroll
                    for (int r = 0; r < 4; ++r) {
                        int tok = mq * 16 + (l4 << 2) + r;
                        Ks[sw(tok, cc, 192)] = f2b(acc[n][r] + qb);
                    }
                } else {
                    int head = cc >> 5, d = cc & 31;
#pragma unroll
                    for (int r = 0; r < 4; ++r) {
                        int tok = mq * 16 + (l4 << 2) + r;
                        Vt[head * 2048 + sw(d, tok, 64)] = f2b(acc[n][r] + qb);
                    }
                }
            }
        }
    }
    __syncthreads();

    // --- Phase 3: attention. 24 units = (head, 16-q-row group) --------------
    {
        bf16* Pw = Pb + wave * 1024;   // wave-private [16][64] swz
#pragma unroll 1
        for (int ui = 0; ui < 2; ++ui) {
            int u = wave + ui * 16;
            if (u >= 24) break;
            int h = u >> 2, mqu = u & 3;
            // QK^T: S[16 q][64 key], K=32
            f32x4 S[4];
            bf16x8 qa = *(const bf16x8*)&Qs[sw(mqu * 16 + l15, h * 32 + kk0, 192)];
#pragma unroll
            for (int n = 0; n < 4; ++n) {
                bf16x8 kb = *(const bf16x8*)&Ks[sw(n * 16 + l15, h * 32 + kk0, 192)];
                S[n] = __builtin_amdgcn_mfma_f32_16x16x32_bf16(qa, kb, (f32x4){0.f,0.f,0.f,0.f}, 0, 0, 0);
            }
            // + precomputed bias/mask, row softmax (row = (l4,r), 16 lanes)
            float inv[4];
#pragma unroll
            for (int r = 0; r < 4; ++r) {
                float vv[4];
                float best = -1e30f;
#pragma unroll
                for (int n = 0; n < 4; ++n) {
                    float v = S[n][r] + bias4[ui][n][r];
                    vv[n] = v;
                    best = fmaxf(best, v);
                }
#pragma unroll
                for (int o = 1; o < 16; o <<= 1) best = fmaxf(best, __shfl_xor(best, o));
                float ssum = 0.f;
#pragma unroll
                for (int n = 0; n < 4; ++n) { vv[n] = __expf(vv[n] - best); ssum += vv[n]; }
#pragma unroll
                for (int o = 1; o < 16; o <<= 1) ssum += __shfl_xor(ssum, o);
                inv[r] = 1.f / ssum;
                int qloc = (l4 << 2) + r;
#pragma unroll
                for (int n = 0; n < 4; ++n)
                    Pw[sw(qloc, n * 16 + l15, 64)] = f2b(vv[n]);   // unnormalized P
            }
            // wave-local LDS transpose: DS pipe in-order per wave
            asm volatile("s_waitcnt lgkmcnt(0)" ::: "memory");
            // PV: out[16 q][32 d] = P[16][64] x V[64][32]
            f32x4 O[2];
#pragma unroll
            for (int n = 0; n < 2; ++n) O[n] = (f32x4){0.f, 0.f, 0.f, 0.f};
#pragma unroll
            for (int ksub = 0; ksub < 2; ++ksub) {
                int kk = ksub * 32 + kk0;
                bf16x8 pa = *(const bf16x8*)&Pw[sw(l15, kk, 64)];
#pragma unroll
                for (int n = 0; n < 2; ++n) {
                    bf16x8 vb = *(const bf16x8*)&Vt[h * 2048 + sw(n * 16 + l15, kk, 64)];
                    O[n] = __builtin_amdgcn_mfma_f32_16x16x32_bf16(pa, vb, O[n], 0, 0, 0);
                }
            }
#pragma unroll
            for (int n = 0; n < 2; ++n)
#pragma unroll
            for (int r = 0; r < 4; ++r) {
                int q = mqu * 16 + (l4 << 2) + r;
                AO[sw(q, h * 32 + n * 16 + l15, 192)] = f2b(O[n][r] * inv[r]);
            }
        }
    }
    __syncthreads();

    // --- Phase 4: proj GEMM + residual(x) -> o1f (LDS fp32) -----------------
    // (Ks/Vt are dead: all PV reads completed before the phase-3-end barrier)
    {
        const bf16* Wp = wsb + WP_OFF;
        int cb0 = cg * 3;
        f32x4 acc[3];
#pragma unroll
        for (int n = 0; n < 3; ++n) acc[n] = (f32x4){0.f, 0.f, 0.f, 0.f};
#pragma unroll
        for (int ks = 0; ks < 6; ++ks) {
            int kk = ks * 32 + kk0;
            bf16x8 a = *(const bf16x8*)&AO[sw(mq * 16 + l15, kk, 192)];
            bf16x8 bb[3];
#pragma unroll
            for (int n = 0; n < 3; ++n)
                bb[n] = *(const bf16x8*)&Wp[((cb0 + n) * 6 + ks) * 512 + (lane << 3)];
#pragma unroll
            for (int n = 0; n < 3; ++n)
                acc[n] = __builtin_amdgcn_mfma_f32_16x16x32_bf16(a, bb[n], acc[n], 0, 0, 0);
        }
        // residual: P1's source address == this token's output address
#pragma unroll
        for (int n = 0; n < 3; ++n) {
            int col = cg * 48 + n * 16 + l15;
            float pb = pbias[col];
#pragma unroll
            for (int r = 0; r < 4; ++r) {
                int tok = mq * 16 + (l4 << 2) + r;
                int i = tok >> 3, j = tok & 7;
                int dh = (wh * 8 + i + 4) & 127;
                int dw = (ww * 8 + j + 4) & 127;
                size_t dst = ((size_t)bz * 16384 + dh * 128 + dw) * 192 + col;
                o1f[tok * 192 + col] = acc[n][r] + pb + x[dst];   // x: L2 hit
            }
        }
    }
    __syncthreads();

    // --- Phase 5: LN2 (from LDS) -> As --------------------------------------
    {
        float g0 = g2[lane], g1 = g2[lane + 64], gx = g2[lane + 128];
        float c0 = bt2[lane], c1 = bt2[lane + 64], c2 = bt2[lane + 128];
        for (int t = wave; t < 64; t += 16) {
            const float* px = o1f + t * 192;
            float v0 = px[lane], v1 = px[lane + 64], v2 = px[lane + 128];
            float s = v0 + v1 + v2, ss = v0 * v0 + v1 * v1 + v2 * v2;
#pragma unroll
            for (int o = 32; o > 0; o >>= 1) { s += __shfl_xor(s, o); ss += __shfl_xor(ss, o); }
            float mu = s * (1.f / 192.f);
            float var = fmaxf(ss * (1.f / 192.f) - mu * mu, 0.f);
            float rs = rsqrtf(var + 1e-5f);
            As[sw(t, lane, 192)]       = f2b((v0 - mu) * rs * g0 + c0);
            As[sw(t, lane + 64, 192)]  = f2b((v1 - mu) * rs * g1 + c1);
            As[sw(t, lane + 128, 192)] = f2b((v2 - mu) * rs * gx + c2);
        }
    }
    __syncthreads();

    // --- Phase 6: MLP, chunked fc1 (6x128 cols) dbuf + fc2 accumulation -----
    {
        const bf16* W1 = wsb + W1_OFF;
        const bf16* W2 = wsb + W2_OFF;
        bf16* Hs[2] = {Hs0, Hs1};
        bf16x8 a6[6];   // As fragments, reused by every fc1 chunk
#pragma unroll
        for (int ks = 0; ks < 6; ++ks)
            a6[ks] = *(const bf16x8*)&As[sw(mq * 16 + l15, ks * 32 + kk0, 192)];

        f32x4 acc2[3];   // fc2 partials: rows mq*16, cols cg*48
#pragma unroll
        for (int n = 0; n < 3; ++n) acc2[n] = (f32x4){0.f, 0.f, 0.f, 0.f};

        auto FC1 = [&](int c, int buf) {
            f32x4 acc1[2];
#pragma unroll
            for (int n = 0; n < 2; ++n) acc1[n] = (f32x4){0.f, 0.f, 0.f, 0.f};
            int cb0 = c * 8 + cg * 2;
#pragma unroll
            for (int ks = 0; ks < 6; ++ks) {
                bf16x8 bb[2];
#pragma unroll
                for (int n = 0; n < 2; ++n)
                    bb[n] = *(const bf16x8*)&W1[((cb0 + n) * 6 + ks) * 512 + (lane << 3)];
#pragma unroll
                for (int n = 0; n < 2; ++n)
                    acc1[n] = __builtin_amdgcn_mfma_f32_16x16x32_bf16(a6[ks], bb[n], acc1[n], 0, 0, 0);
            }
#pragma unroll
            for (int n = 0; n < 2; ++n) {
                int colc = cg * 32 + n * 16 + l15;
                float bb1 = b1[c * 128 + colc];
#pragma unroll
                for (int r = 0; r < 4; ++r) {
                    int tok = mq * 16 + (l4 << 2) + r;
                    float v = acc1[n][r] + bb1;
                    v = v > 0.f ? v : 0.2f * v;
                    Hs[buf][sw(tok, colc, 128)] = f2b(v);
                }
            }
        };

        FC1(0, 0);
        __syncthreads();
#pragma unroll 1
        for (int c = 0; c < 6; ++c) {
            if (c < 5) FC1(c + 1, (c + 1) & 1);
            // fc2 partial from Hs[c&1]: K += 128
#pragma unroll
            for (int ks = 0; ks < 4; ++ks) {
                int kk = ks * 32 + kk0;
                bf16x8 a = *(const bf16x8*)&Hs[c & 1][sw(mq * 16 + l15, kk, 128)];
                bf16x8 bb[3];
#pragma unroll
                for (int n = 0; n < 3; ++n)
                    bb[n] = *(const bf16x8*)&W2[((cg * 3 + n) * 24 + c * 4 + ks) * 512 + (lane << 3)];
#pragma unroll
                for (int n = 0; n < 3; ++n)
                    acc2[n] = __builtin_amdgcn_mfma_f32_16x16x32_bf16(a, bb[n], acc2[n], 0, 0, 0);
            }
            __syncthreads();
        }

        // --- Phase 7: final = o1f + fc2 + b2, window-reverse + un-shift -----
#pragma unroll
        for (int n = 0; n < 3; ++n) {
            int col = cg * 48 + n * 16 + l15;
            float bb2 = b2[col];
#pragma unroll
            for (int r = 0; r < 4; ++r) {
                int tok = mq * 16 + (l4 << 2) + r;
                int i = tok >> 3, j = tok & 7;
                int dh = (wh * 8 + i + 4) & 127;
                int dw = (ww * 8 + j + 4) & 127;
                size_t dst = ((size_t)bz * 16384 + dh * 128 + dw) * 192 + col;
                NTS(acc2[n][r] + bb2 + o1f[tok * 192 + col], &out[dst]);
            }
        }
    }
}

// ---------------- launch ----------------------------------------------------
extern "C" void kernel_launch(void* const* d_in, const int* in_sizes, int n_in,
                              void* d_out, int out_size, void* d_ws, size_t ws_size,
                              hipStream_t stream) {
    const float* x     = (const float*)d_in[0];
    const float* n1g   = (const float*)d_in[1];
    const float* n1b   = (const float*)d_in[2];
    const float* qkvw  = (const float*)d_in[3];
    const float* qkvb  = (const float*)d_in[4];
    const float* projw = (const float*)d_in[5];
    const float* projb = (const float*)d_in[6];
    const float* rpb   = (const float*)d_in[7];
    const float* n2g   = (const float*)d_in[8];
    const float* n2b   = (const float*)d_in[9];
    const float* fc1w  = (const float*)d_in[10];
    const float* fc1b  = (const float*)d_in[11];
    const float* fc2w  = (const float*)d_in[12];
    const float* fc2b  = (const float*)d_in[13];

    float* out = (float*)d_out;
    bf16* wsb  = (bf16*)d_ws;                       // 884736 B weights
    float* bws = (float*)((char*)d_ws + 884736);    // 393216 B bias table
    (void)ws_size; (void)in_sizes; (void)n_in; (void)out_size;

    w_cvt<<<216, 256, 0, stream>>>(qkvw, projw, fc1w, fc2w, wsb);
    b_cvt<<<384, 256, 0, stream>>>(rpb, bws);
    k_all<<<2048, 1024, 0, stream>>>(x, n1g, n1b, wsb, bws, qkvb, projb,
                                     n2g, n2b, fc1b, fc2b, out);
}

// Round 6
// 550.175 us; speedup vs baseline: 1.1671x; 1.1671x over previous
//
#include <hip/hip_runtime.h>
#include <hip/hip_bf16.h>

// Swin block: B=8, H=W=128, C=192, NH=6, HD=32, WS=8, SHIFT=4, N=64, NW=256
// ROUND 12: L2-weight-stream attack on the fused kernel.
//  - m=4 GEMM partition: each weight B-frag feeds 4 MFMAs (was 1) -> per-block
//    weight traffic 3.5MB -> 0.86MB (R11 analysis: ~215us of L2 streaming).
//  - bias table stored bf16 (halves the 200MB bias stream).
//  - single merged prep kernel (R11: two tiny launches cost 119us).
//  - o1f fp32 tile XOR-swizzled (4-way bank conflict in P4/P7 -> ~2-way).
//  - MLP: 2 chunks x 384 cols, single Hs buffer, 8 barriers total (was 12).

typedef __hip_bfloat16 bf16;
typedef short bf16x8 __attribute__((ext_vector_type(8)));   // 8 bf16 = 4 VGPRs
typedef float f32x4 __attribute__((ext_vector_type(4)));

__device__ __forceinline__ bf16 f2b(float f) { return __float2bfloat16(f); }
__device__ __forceinline__ float bits2f(short u) {   // bf16 bits -> f32 (exact)
    unsigned int x = ((unsigned int)(unsigned short)u) << 16;
    float f; __builtin_memcpy(&f, &x, 4); return f;
}
// bf16 LDS swizzle: XOR row low bits into the 16B-granule index (8 bf16).
__device__ __forceinline__ int sw(int row, int col, int stride) {
    return row * stride + (col ^ ((row & 7) << 3));
}
// f32 LDS swizzle: XOR row low bits into the 16B-granule index (4 f32).
__device__ __forceinline__ int swf(int row, int col) {
    return row * 192 + (col ^ ((row & 7) << 2));
}
#define NTS(v, p) __builtin_nontemporal_store(v, p)

// workspace: fragment-ordered bf16 weights, then bf16 bias table.
// weight element ((cb*KS + ks)*64 + lane)*8 + j == W[cb*16+(lane&15)][ks*32+(lane>>4)*8+j]
#define WQ_OFF 0        // qkv_w  [576][192]  cb=36 KS=6
#define WP_OFF 110592   // proj_w [192][192]  cb=12 KS=6
#define W1_OFF 147456   // fc1_w  [768][192]  cb=48 KS=6
#define W2_OFF 294912   // fc2_w  [192][768]  cb=12 KS=24
#define WS_ELEMS 442368
// bias table: bf16 [type(4)][u(24)][lane(64)][n(4)][r(4)]  (196608 B)

// ---- K0: merged prep: weight cvt (blocks 0..215) + bias table (216..599) ---
__global__ __launch_bounds__(256) void prep(const float* __restrict__ qw,
                                            const float* __restrict__ pw,
                                            const float* __restrict__ w1,
                                            const float* __restrict__ w2,
                                            const float* __restrict__ rpb,
                                            bf16* __restrict__ ws,
                                            bf16* __restrict__ bws) {
    if (blockIdx.x < 216) {
        int t = blockIdx.x * 256 + threadIdx.x;   // [0, 55296)
        const float* src; int K; int base; int g;
        if (t < 13824)      { src = qw; K = 192; base = WQ_OFF; g = t; }
        else if (t < 18432) { src = pw; K = 192; base = WP_OFF; g = t - 13824; }
        else if (t < 36864) { src = w1; K = 192; base = W1_OFF; g = t - 18432; }
        else                { src = w2; K = 768; base = W2_OFF; g = t - 36864; }
        int KS = K >> 5;
        int cb   = g / (KS * 64);
        int rem  = g % (KS * 64);
        int ks   = rem >> 6;
        int lane = rem & 63;
        int row  = cb * 16 + (lane & 15);
        int k0   = ks * 32 + (lane >> 4) * 8;
        bf16* dst = ws + base + (size_t)g * 8;
        const float* s = src + (size_t)row * K + k0;
#pragma unroll
        for (int j = 0; j < 8; ++j) dst[j] = f2b(s[j]);
    } else {
        int i = (blockIdx.x - 216) * 256 + threadIdx.x;   // [0, 98304)
        int r = i & 3, n = (i >> 2) & 3, lane = (i >> 4) & 63;
        int rest = i >> 10;
        int u = rest % 24, type = rest / 24;
        int h = u >> 2, mq = u & 3;
        int q   = mq * 16 + (lane >> 4) * 4 + r;
        int key = n * 16 + (lane & 15);
        int yi = q >> 3, xi = q & 7, yj = key >> 3, xj = key & 7;
        float b = rpb[((yi - yj + 7) * 15 + (xi - xj + 7)) * 6 + h];
        int ty = type >> 1, tx = type & 1;
        int li = (ty ? (yi < 4 ? 1 : 2) : 0) * 3 + (tx ? (xi < 4 ? 1 : 2) : 0);
        int lj = (ty ? (yj < 4 ? 1 : 2) : 0) * 3 + (tx ? (xj < 4 ? 1 : 2) : 0);
        if (li != lj) b -= 100.f;
        bws[i] = f2b(b);
    }
}

// ---- K1: fully fused Swin block, one window (64 tokens) per block ----------
__global__ __launch_bounds__(1024, 4) void k_all(const float* __restrict__ x,
                                                 const float* __restrict__ g,
                                                 const float* __restrict__ bt,
                                                 const bf16* __restrict__ wsb,
                                                 const bf16* __restrict__ bws,
                                                 const float* __restrict__ qbias,
                                                 const float* __restrict__ pbias,
                                                 const float* __restrict__ g2,
                                                 const float* __restrict__ bt2,
                                                 const float* __restrict__ b1,
                                                 const float* __restrict__ b2,
                                                 float* __restrict__ out) {
    // LDS (128 KB), regions reused across phases:
    //  R0 [0,24576)      Qs [64][192]swz         | P5+: As (LN2 tile)
    //  R1 [24576,49152)  Ks [64][192]swz         | P4+: o1f fp32 [64][192]swf
    //  R2 [49152,73728)  Vt [6][32][64]swz       |      (48KB, spans R1+R2)
    //  R3 [73728,98304)  A (LN1) == AO           | P6+: Hs [64][384]swz bf16
    //  R4 [98304,131072) Pb 16x2KB               |      (48KB, spans R3+24KB of R4)
    __shared__ __align__(16) char SM[131072];
    bf16* Qs = (bf16*)(SM);
    bf16* Ks = (bf16*)(SM + 24576);
    bf16* Vt = (bf16*)(SM + 49152);
    bf16* A  = (bf16*)(SM + 73728);
    bf16* AO = (bf16*)(SM + 73728);
    bf16* Pb = (bf16*)(SM + 98304);
    float* o1f = (float*)(SM + 24576);   // overlays Ks+Vt (dead after P3)
    bf16* As   = (bf16*)(SM);            // overlays Qs (dead after P3)
    bf16* Hs   = (bf16*)(SM + 73728);    // overlays AO+Pb (dead after P4/P3)

    int wid = blockIdx.x;
    int bz = wid >> 8, widx = wid & 255;
    int wh = widx >> 4, ww = widx & 15;
    int tid = threadIdx.x, wave = tid >> 6, lane = tid & 63;
    int l15 = lane & 15, l4 = lane >> 4;
    int kk0 = l4 << 3;
    const float SC = 0.1767766952966369f;  // 1/sqrt(32)

    // --- Phase 0: this wave's softmax bias fragments (bf16, consumed P3) ----
    int wtype = ((wh == 15) ? 2 : 0) | ((ww == 15) ? 1 : 0);
    bf16x8 bias8[2][2];
    {
        const bf16* bp = bws + (((size_t)wtype * 24 + wave) * 64 + lane) * 16;
        bias8[0][0] = *(const bf16x8*)bp;
        bias8[0][1] = *(const bf16x8*)(bp + 8);
        if (wave < 8) {
            const bf16* bp2 = bws + (((size_t)wtype * 24 + wave + 16) * 64 + lane) * 16;
            bias8[1][0] = *(const bf16x8*)bp2;
            bias8[1][1] = *(const bf16x8*)(bp2 + 8);
        }
    }

    // --- Phase 1: LN1 + cyclic shift -> A -----------------------------------
    {
        float g0 = g[lane], g1 = g[lane + 64], gx = g[lane + 128];
        float c0 = bt[lane], c1 = bt[lane + 64], c2 = bt[lane + 128];
        for (int t = wave; t < 64; t += 16) {
            int i = t >> 3, j = t & 7;
            int shr = (wh * 8 + i + 4) & 127;   // roll(-4)
            int shc = (ww * 8 + j + 4) & 127;
            const float* px = x + ((size_t)bz * 16384 + shr * 128 + shc) * 192;
            float v0 = px[lane], v1 = px[lane + 64], v2 = px[lane + 128];
            float s = v0 + v1 + v2, ss = v0 * v0 + v1 * v1 + v2 * v2;
#pragma unroll
            for (int o = 32; o > 0; o >>= 1) { s += __shfl_xor(s, o); ss += __shfl_xor(ss, o); }
            float mu = s * (1.f / 192.f);
            float var = fmaxf(ss * (1.f / 192.f) - mu * mu, 0.f);
            float rs = rsqrtf(var + 1e-5f);
            A[sw(t, lane, 192)]       = f2b((v0 - mu) * rs * g0 + c0);
            A[sw(t, lane + 64, 192)]  = f2b((v1 - mu) * rs * g1 + c1);
            A[sw(t, lane + 128, 192)] = f2b((v2 - mu) * rs * gx + c2);
        }
    }
    __syncthreads();

    // --- Phase 2: QKV GEMM, m=4 (M=64, N=576, K=192) ------------------------
    // 36 n-frags: every wave does {wave, wave+16}; waves 0-3 also {wave+32}.
    {
        const bf16* Wq = wsb + WQ_OFF;
        int nf = (wave < 4) ? 3 : 2;
#pragma unroll 1
        for (int fi = 0; fi < nf; ++fi) {
            int f = wave + fi * 16;            // 0..35
            f32x4 acc[4];
#pragma unroll
            for (int m = 0; m < 4; ++m) acc[m] = (f32x4){0.f, 0.f, 0.f, 0.f};
#pragma unroll
            for (int ks = 0; ks < 6; ++ks) {
                bf16x8 bb = *(const bf16x8*)&Wq[(f * 6 + ks) * 512 + (lane << 3)];
#pragma unroll
                for (int m = 0; m < 4; ++m) {
                    bf16x8 a = *(const bf16x8*)&A[sw(m * 16 + l15, ks * 32 + kk0, 192)];
                    acc[m] = __builtin_amdgcn_mfma_f32_16x16x32_bf16(a, bb, acc[m], 0, 0, 0);
                }
            }
            int which = f / 12, cc = (f % 12) * 16 + l15;   // which wave-uniform
            float qb = qbias[which * 192 + cc];
            if (which == 0) {
#pragma unroll
                for (int m = 0; m < 4; ++m)
#pragma unroll
                for (int r = 0; r < 4; ++r)
                    Qs[sw(m * 16 + (l4 << 2) + r, cc, 192)] = f2b((acc[m][r] + qb) * SC);
            } else if (which == 1) {
#pragma unroll
                for (int m = 0; m < 4; ++m)
#pragma unroll
                for (int r = 0; r < 4; ++r)
                    Ks[sw(m * 16 + (l4 << 2) + r, cc, 192)] = f2b(acc[m][r] + qb);
            } else {
                int head = (f % 12) >> 1, d = cc & 31;
#pragma unroll
                for (int m = 0; m < 4; ++m)
#pragma unroll
                for (int r = 0; r < 4; ++r)
                    Vt[head * 2048 + sw(d, m * 16 + (l4 << 2) + r, 64)] = f2b(acc[m][r] + qb);
            }
        }
    }
    __syncthreads();

    // --- Phase 3: attention. 24 units = (head, 16-q-row group) --------------
    {
        bf16* Pw = Pb + wave * 1024;   // wave-private [16][64] swz
#pragma unroll 1
        for (int ui = 0; ui < 2; ++ui) {
            int u = wave + ui * 16;
            if (u >= 24) break;
            int h = u >> 2, mqu = u & 3;
            // QK^T: S[16 q][64 key], K=32
            f32x4 S[4];
            bf16x8 qa = *(const bf16x8*)&Qs[sw(mqu * 16 + l15, h * 32 + kk0, 192)];
#pragma unroll
            for (int n = 0; n < 4; ++n) {
                bf16x8 kb = *(const bf16x8*)&Ks[sw(n * 16 + l15, h * 32 + kk0, 192)];
                S[n] = __builtin_amdgcn_mfma_f32_16x16x32_bf16(qa, kb, (f32x4){0.f,0.f,0.f,0.f}, 0, 0, 0);
            }
            // + bias/mask (bf16 frags), row softmax (row = (l4,r), 16 lanes)
            float inv[4];
#pragma unroll
            for (int r = 0; r < 4; ++r) {
                float vv[4];
                float best = -1e30f;
#pragma unroll
                for (int n = 0; n < 4; ++n) {
                    int idx = n * 4 + r;
                    float bv = (idx < 8) ? bits2f(bias8[ui][0][idx])
                                         : bits2f(bias8[ui][1][idx - 8]);
                    float v = S[n][r] + bv;
                    vv[n] = v;
                    best = fmaxf(best, v);
                }
#pragma unroll
                for (int o = 1; o < 16; o <<= 1) best = fmaxf(best, __shfl_xor(best, o));
                float ssum = 0.f;
#pragma unroll
                for (int n = 0; n < 4; ++n) { vv[n] = __expf(vv[n] - best); ssum += vv[n]; }
#pragma unroll
                for (int o = 1; o < 16; o <<= 1) ssum += __shfl_xor(ssum, o);
                inv[r] = 1.f / ssum;
                int qloc = (l4 << 2) + r;
#pragma unroll
                for (int n = 0; n < 4; ++n)
                    Pw[sw(qloc, n * 16 + l15, 64)] = f2b(vv[n]);   // unnormalized P
            }
            // wave-local LDS transpose: DS pipe in-order per wave
            asm volatile("s_waitcnt lgkmcnt(0)" ::: "memory");
            // PV: out[16 q][32 d] = P[16][64] x V[64][32]
            f32x4 O[2];
#pragma unroll
            for (int n = 0; n < 2; ++n) O[n] = (f32x4){0.f, 0.f, 0.f, 0.f};
#pragma unroll
            for (int ksub = 0; ksub < 2; ++ksub) {
                int kk = ksub * 32 + kk0;
                bf16x8 pa = *(const bf16x8*)&Pw[sw(l15, kk, 64)];
#pragma unroll
                for (int n = 0; n < 2; ++n) {
                    bf16x8 vb = *(const bf16x8*)&Vt[h * 2048 + sw(n * 16 + l15, kk, 64)];
                    O[n] = __builtin_amdgcn_mfma_f32_16x16x32_bf16(pa, vb, O[n], 0, 0, 0);
                }
            }
#pragma unroll
            for (int n = 0; n < 2; ++n)
#pragma unroll
            for (int r = 0; r < 4; ++r) {
                int q = mqu * 16 + (l4 << 2) + r;
                AO[sw(q, h * 32 + n * 16 + l15, 192)] = f2b(O[n][r] * inv[r]);
            }
        }
    }
    __syncthreads();

    // --- Phase 4: proj GEMM m=4 (waves 0-11) + residual(x) -> o1f (swf) -----
    if (wave < 12) {
        const bf16* Wp = wsb + WP_OFF;
        int f = wave;                      // n-frag 0..11
        f32x4 acc[4];
#pragma unroll
        for (int m = 0; m < 4; ++m) acc[m] = (f32x4){0.f, 0.f, 0.f, 0.f};
#pragma unroll
        for (int ks = 0; ks < 6; ++ks) {
            bf16x8 bb = *(const bf16x8*)&Wp[(f * 6 + ks) * 512 + (lane << 3)];
#pragma unroll
            for (int m = 0; m < 4; ++m) {
                bf16x8 a = *(const bf16x8*)&AO[sw(m * 16 + l15, ks * 32 + kk0, 192)];
                acc[m] = __builtin_amdgcn_mfma_f32_16x16x32_bf16(a, bb, acc[m], 0, 0, 0);
            }
        }
        int col = f * 16 + l15;
        float pb = pbias[col];
#pragma unroll
        for (int m = 0; m < 4; ++m)
#pragma unroll
        for (int r = 0; r < 4; ++r) {
            int tok = m * 16 + (l4 << 2) + r;
            int i = tok >> 3, j = tok & 7;
            int dh = (wh * 8 + i + 4) & 127;
            int dw = (ww * 8 + j + 4) & 127;
            size_t dst = ((size_t)bz * 16384 + dh * 128 + dw) * 192 + col;
            o1f[swf(tok, col)] = acc[m][r] + pb + x[dst];   // x: L2 hit
        }
    }
    __syncthreads();

    // --- Phase 5: LN2 (from LDS) -> As --------------------------------------
    {
        float g0 = g2[lane], g1 = g2[lane + 64], gx = g2[lane + 128];
        float c0 = bt2[lane], c1 = bt2[lane + 64], c2 = bt2[lane + 128];
        for (int t = wave; t < 64; t += 16) {
            float v0 = o1f[swf(t, lane)], v1 = o1f[swf(t, lane + 64)], v2 = o1f[swf(t, lane + 128)];
            float s = v0 + v1 + v2, ss = v0 * v0 + v1 * v1 + v2 * v2;
#pragma unroll
            for (int o = 32; o > 0; o >>= 1) { s += __shfl_xor(s, o); ss += __shfl_xor(ss, o); }
            float mu = s * (1.f / 192.f);
            float var = fmaxf(ss * (1.f / 192.f) - mu * mu, 0.f);
            float rs = rsqrtf(var + 1e-5f);
            As[sw(t, lane, 192)]       = f2b((v0 - mu) * rs * g0 + c0);
            As[sw(t, lane + 64, 192)]  = f2b((v1 - mu) * rs * g1 + c1);
            As[sw(t, lane + 128, 192)] = f2b((v2 - mu) * rs * gx + c2);
        }
    }
    __syncthreads();

    // --- Phase 6: MLP m=4, 2 chunks x 384 cols, single Hs buffer ------------
    {
        const bf16* W1 = wsb + W1_OFF;
        const bf16* W2 = wsb + W2_OFF;
        f32x4 acc2[4];   // fc2 persistent partials: n-frag = wave (waves 0-11)
#pragma unroll
        for (int m = 0; m < 4; ++m) acc2[m] = (f32x4){0.f, 0.f, 0.f, 0.f};

#pragma unroll 1
        for (int ch = 0; ch < 2; ++ch) {
            // fc1 chunk: 24 n-frags: all waves {wave}; waves 0-7 also {wave+16}
            int nf = (wave < 8) ? 2 : 1;
#pragma unroll 1
            for (int fi = 0; fi < nf; ++fi) {
                int fl = wave + fi * 16;       // 0..23 within chunk
                int gf = ch * 24 + fl;         // 0..47 global
                f32x4 acc[4];
#pragma unroll
                for (int m = 0; m < 4; ++m) acc[m] = (f32x4){0.f, 0.f, 0.f, 0.f};
#pragma unroll
                for (int ks = 0; ks < 6; ++ks) {
                    bf16x8 bb = *(const bf16x8*)&W1[(gf * 6 + ks) * 512 + (lane << 3)];
#pragma unroll
                    for (int m = 0; m < 4; ++m) {
                        bf16x8 a = *(const bf16x8*)&As[sw(m * 16 + l15, ks * 32 + kk0, 192)];
                        acc[m] = __builtin_amdgcn_mfma_f32_16x16x32_bf16(a, bb, acc[m], 0, 0, 0);
                    }
                }
                int colc = fl * 16 + l15;      // col within chunk [0,384)
                float bb1 = b1[gf * 16 + l15];
#pragma unroll
                for (int m = 0; m < 4; ++m)
#pragma unroll
                for (int r = 0; r < 4; ++r) {
                    float v = acc[m][r] + bb1;
                    v = v > 0.f ? v : 0.2f * v;
                    Hs[sw(m * 16 + (l4 << 2) + r, colc, 384)] = f2b(v);
                }
            }
            __syncthreads();
            // fc2 partial: waves 0-11, n-frag = wave, K += 384
            if (wave < 12) {
#pragma unroll
                for (int ks = 0; ks < 12; ++ks) {
                    bf16x8 bb = *(const bf16x8*)&W2[(wave * 24 + ch * 12 + ks) * 512 + (lane << 3)];
#pragma unroll
                    for (int m = 0; m < 4; ++m) {
                        bf16x8 a = *(const bf16x8*)&Hs[sw(m * 16 + l15, ks * 32 + kk0, 384)];
                        acc2[m] = __builtin_amdgcn_mfma_f32_16x16x32_bf16(a, bb, acc2[m], 0, 0, 0);
                    }
                }
            }
            if (ch == 0) __syncthreads();   // next fc1 overwrites Hs
        }

        // --- Phase 7: final = o1f + fc2 + b2, window-reverse + un-shift -----
        if (wave < 12) {
            int col = wave * 16 + l15;
            float bb2 = b2[col];
#pragma unroll
            for (int m = 0; m < 4; ++m)
#pragma unroll
            for (int r = 0; r < 4; ++r) {
                int tok = m * 16 + (l4 << 2) + r;
                int i = tok >> 3, j = tok & 7;
                int dh = (wh * 8 + i + 4) & 127;
                int dw = (ww * 8 + j + 4) & 127;
                size_t dst = ((size_t)bz * 16384 + dh * 128 + dw) * 192 + col;
                NTS(acc2[m][r] + bb2 + o1f[swf(tok, col)], &out[dst]);
            }
        }
    }
}

// ---------------- launch ----------------------------------------------------
extern "C" void kernel_launch(void* const* d_in, const int* in_sizes, int n_in,
                              void* d_out, int out_size, void* d_ws, size_t ws_size,
                              hipStream_t stream) {
    const float* x     = (const float*)d_in[0];
    const float* n1g   = (const float*)d_in[1];
    const float* n1b   = (const float*)d_in[2];
    const float* qkvw  = (const float*)d_in[3];
    const float* qkvb  = (const float*)d_in[4];
    const float* projw = (const float*)d_in[5];
    const float* projb = (const float*)d_in[6];
    const float* rpb   = (const float*)d_in[7];
    const float* n2g   = (const float*)d_in[8];
    const float* n2b   = (const float*)d_in[9];
    const float* fc1w  = (const float*)d_in[10];
    const float* fc1b  = (const float*)d_in[11];
    const float* fc2w  = (const float*)d_in[12];
    const float* fc2b  = (const float*)d_in[13];

    float* out = (float*)d_out;
    bf16* wsb  = (bf16*)d_ws;                       // 884736 B weights
    bf16* bws  = (bf16*)((char*)d_ws + 884736);     // 196608 B bias table (bf16)
    (void)ws_size; (void)in_sizes; (void)n_in; (void)out_size;

    prep<<<600, 256, 0, stream>>>(qkvw, projw, fc1w, fc2w, rpb, wsb, bws);
    k_all<<<2048, 1024, 0, stream>>>(x, n1g, n1b, wsb, bws, qkvb, projb,
                                     n2g, n2b, fc1b, fc2b, out);
}